// Round 4
// baseline (94.831 us; speedup 1.0000x reference)
//
#include <hip/hip_runtime.h>
#include <hip/hip_bf16.h>

// Model dims (fixed by the reference)
#define R_ 64
#define S_ 32
#define T_ 50
#define E_ 512
#define U_ 20
#define D_ 532   // E + U
#define L_ 9
#define NSENT (R_ * S_)   // 2048

#define PCHUNK 128
#define NCG 5   // ceil(532/128) column groups
#define NKG 5   // ceil(532/128) k groups

typedef __attribute__((ext_vector_type(8))) short bf16x8;
typedef __attribute__((ext_vector_type(4))) float f32x4;

__device__ __forceinline__ float selu_f(float x) {
    const float scale = 1.0507009873554805f;
    const float alpha = 1.6732632423543772f;
    return x > 0.0f ? scale * x : scale * alpha * expm1f(x);
}

// Kernel A (fused): blocks [0,2048) = per-sentence masked token-mean -> bf16;
// blocks [2048,2304) = transpose-convert w_sent fp32 [k][n] -> bf16 wT[n][k].
__global__ __launch_bounds__(256) void k_fused_A(
        const int* __restrict__ inputs,       // [R,S,T]
        const float* __restrict__ emb,        // [V,E]
        const float* __restrict__ w_sent,     // [512,512]
        __hip_bfloat16* __restrict__ sent_bf, // out [2048,512] bf16
        __hip_bfloat16* __restrict__ wT,      // out [512,512] bf16 (transposed)
        float* __restrict__ smask)            // out [2048]
{
    __shared__ float red[2][E_];
    __shared__ int scnt[2], ssum[2];
    __shared__ float tile[32][33];
    const int tid = threadIdx.x;

    if (blockIdx.x >= NSENT) {
        // ---- w_sent transpose-convert: 256 blocks of 32x32 tiles ----
        const int b = blockIdx.x - NSENT;
        const int tx = tid & 31, ty = tid >> 5;           // ty 0..7
        const int k0 = (b >> 4) * 32, n0 = (b & 15) * 32;
        #pragma unroll
        for (int i = 0; i < 4; ++i)
            tile[ty + 8 * i][tx] = w_sent[(size_t)(k0 + ty + 8 * i) * E_ + n0 + tx];
        __syncthreads();
        #pragma unroll
        for (int i = 0; i < 4; ++i)
            wT[(size_t)(n0 + ty + 8 * i) * E_ + k0 + tx] = __float2bfloat16(tile[tx][ty + 8 * i]);
        return;
    }

    // ---- sentence masked mean ----
    const int sid = blockIdx.x;
    const int c4 = (tid & 127) * 4;   // column base (float4 granularity)
    const int half = tid >> 7;        // 0/1: even/odd tokens
    float4 acc = {0.f, 0.f, 0.f, 0.f};
    int cnt = 0, idsum = 0;
    #pragma unroll
    for (int t = half; t < T_; t += 2) {
        const int tok = inputs[sid * T_ + t];          // wave-uniform -> scalar load
        const float m = (tok != 0) ? 1.0f : 0.0f;
        cnt += (tok != 0);
        idsum += tok;
        // unconditional gather (tok==0 reads row 0, nullified by m) -> pipelinable
        const float4 v = *(const float4*)(emb + (size_t)tok * E_ + c4);
        acc.x = fmaf(v.x, m, acc.x);
        acc.y = fmaf(v.y, m, acc.y);
        acc.z = fmaf(v.z, m, acc.z);
        acc.w = fmaf(v.w, m, acc.w);
    }
    *(float4*)&red[half][c4] = acc;
    if ((tid & 127) == 0) { scnt[half] = cnt; ssum[half] = idsum; }
    __syncthreads();
    if (half == 0) {
        const float4 a = *(const float4*)&red[0][c4];
        const float4 b = *(const float4*)&red[1][c4];
        const float inv = 1.0f / fmaxf((float)(scnt[0] + scnt[1]), 1.0f);
        union { ushort4 u; __hip_bfloat16 h[4]; } o;
        o.h[0] = __float2bfloat16((a.x + b.x) * inv);
        o.h[1] = __float2bfloat16((a.y + b.y) * inv);
        o.h[2] = __float2bfloat16((a.z + b.z) * inv);
        o.h[3] = __float2bfloat16((a.w + b.w) * inv);
        *((ushort4*)(sent_bf + (size_t)sid * E_) + (tid & 127)) = o.u;
        if (tid == 0) smask[sid] = ((ssum[0] + ssum[1]) != 0) ? 1.0f : 0.0f;
    }
}

// Kernel G: C[M,512] = selu(A_bf16[M,512] @ W + bias), W given transposed bf16 (Bt[n][k]).
// 64x64 tile per block, 4 waves in 2x2, each wave 32x32 via 2x2 mfma_f32_16x16x32_bf16.
// grid = (N/64, M/64), block 256.
__global__ __launch_bounds__(256) void k_gemm_selu(
        const __hip_bfloat16* __restrict__ A,   // [M,512]
        const __hip_bfloat16* __restrict__ Bt,  // [512,512]  Bt[n][k]
        const float* __restrict__ bias,         // [512]
        __hip_bfloat16* __restrict__ C, int ldc)
{
    __shared__ short As[64][40];   // 64 rows x (32 k + 8 pad) bf16
    __shared__ short Bs[64][40];
    const int tid  = threadIdx.x;
    const int wid  = tid >> 6;
    const int lane = tid & 63;
    const int wm = wid >> 1, wn = wid & 1;
    const int bm = blockIdx.y * 64, bn = blockIdx.x * 64;

    const int srow = tid >> 2;         // 0..63
    const int soff = (tid & 3) * 8;    // 0,8,16,24

    const short* Ag  = (const short*)A;
    const short* Btg = (const short*)Bt;

    f32x4 acc[2][2];
    #pragma unroll
    for (int i = 0; i < 2; ++i)
        #pragma unroll
        for (int j = 0; j < 2; ++j) acc[i][j] = (f32x4){0.f, 0.f, 0.f, 0.f};

    const int fr = lane & 15;
    const int kg = (lane >> 4) * 8;

    for (int k0 = 0; k0 < E_; k0 += 32) {
        __syncthreads();
        *(bf16x8*)&As[srow][soff] = *(const bf16x8*)&Ag[(size_t)(bm + srow) * E_ + k0 + soff];
        *(bf16x8*)&Bs[srow][soff] = *(const bf16x8*)&Btg[(size_t)(bn + srow) * E_ + k0 + soff];
        __syncthreads();
        bf16x8 af0 = *(const bf16x8*)&As[wm * 32 + fr][kg];
        bf16x8 af1 = *(const bf16x8*)&As[wm * 32 + 16 + fr][kg];
        bf16x8 bf0 = *(const bf16x8*)&Bs[wn * 32 + fr][kg];
        bf16x8 bf1 = *(const bf16x8*)&Bs[wn * 32 + 16 + fr][kg];
        acc[0][0] = __builtin_amdgcn_mfma_f32_16x16x32_bf16(af0, bf0, acc[0][0], 0, 0, 0);
        acc[0][1] = __builtin_amdgcn_mfma_f32_16x16x32_bf16(af0, bf1, acc[0][1], 0, 0, 0);
        acc[1][0] = __builtin_amdgcn_mfma_f32_16x16x32_bf16(af1, bf0, acc[1][0], 0, 0, 0);
        acc[1][1] = __builtin_amdgcn_mfma_f32_16x16x32_bf16(af1, bf1, acc[1][1], 0, 0, 0);
    }

    // epilogue: C/D mapping col = lane&15, row = (lane>>4)*4 + reg   [m89]
    const int rq = (lane >> 4) * 4;
    #pragma unroll
    for (int fm = 0; fm < 2; ++fm) {
        #pragma unroll
        for (int fn = 0; fn < 2; ++fn) {
            const int col = bn + wn * 32 + fn * 16 + fr;
            const float bv = bias[col];
            #pragma unroll
            for (int j = 0; j < 4; ++j) {
                const int row = bm + wm * 32 + fm * 16 + rq + j;
                C[(size_t)row * ldc + col] = __float2bfloat16(selu_f(acc[fm][fn][j] + bv));
            }
        }
    }
}

// Kernel R (fused rev stage): per-review masked mean (fp32) -> GEMV w_rev (fp32,
// exact reference path) + bias + selu -> prow; user feats; p_batch row; r_stars.
// grid = 64, block 256.
__global__ __launch_bounds__(256) void k_rev_fused(
        const __hip_bfloat16* __restrict__ sent_h,  // [2048,512] bf16
        const float* __restrict__ smask,            // [2048]
        const float* __restrict__ w_rev,            // [512,512] fp32
        const float* __restrict__ b_rev,            // [512]
        const float* __restrict__ user_feats,       // [64,20]
        const float* __restrict__ user_w,           // [20]
        const float* __restrict__ w_rff,            // [532]
        const float* __restrict__ b_rff,            // [1]
        float* __restrict__ p_batch,                // out [64,532]
        float* __restrict__ out_r)                  // out r_stars [64]
{
    __shared__ float mrow[E_];
    __shared__ float prow[D_];
    __shared__ float wsum[4];
    const int r = blockIdx.x;
    const int tid = threadIdx.x;

    // masked mean over S sentences (2 cols/thread)
    float2 acc = {0.f, 0.f};
    float msum = 0.f;
    for (int s = 0; s < S_; ++s) {
        const float m = smask[r * S_ + s];
        const __hip_bfloat162 v = ((const __hip_bfloat162*)(sent_h + (size_t)(r * S_ + s) * E_))[tid];
        acc.x = fmaf(__bfloat162float(v.x), m, acc.x);
        acc.y = fmaf(__bfloat162float(v.y), m, acc.y);
        msum += m;
    }
    const float inv = 1.0f / fmaxf(msum, 1.0f);
    mrow[2 * tid]     = acc.x * inv;
    mrow[2 * tid + 1] = acc.y * inv;
    __syncthreads();

    // rev_h = selu(mrow @ w_rev + b_rev), cols tid and tid+256
    float a0 = 0.f, a1 = 0.f;
    for (int k = 0; k < E_; ++k) {
        const float xv = mrow[k];
        a0 = fmaf(xv, w_rev[(size_t)k * E_ + tid], a0);
        a1 = fmaf(xv, w_rev[(size_t)k * E_ + tid + 256], a1);
    }
    prow[tid]       = selu_f(a0 + b_rev[tid]);
    prow[tid + 256] = selu_f(a1 + b_rev[tid + 256]);

    if (tid < U_) {
        float ss = 0.f;
        #pragma unroll
        for (int j = 0; j < U_; ++j) {
            const float u = user_feats[r * U_ + j];
            ss = fmaf(u, u, ss);
        }
        const float nrm = fmaxf(sqrtf(ss), 1e-12f);
        prow[E_ + tid] = user_feats[r * U_ + tid] / nrm * user_w[tid];
    }
    __syncthreads();

    // p_batch row
    p_batch[(size_t)r * D_ + tid]       = prow[tid];
    p_batch[(size_t)r * D_ + tid + 256] = prow[tid + 256];
    if (tid < D_ - 512) p_batch[(size_t)r * D_ + 512 + tid] = prow[512 + tid];

    // r_star = selu(prow . w_rff + b_rff)
    float part = 0.f;
    for (int k = tid; k < D_; k += 256) part = fmaf(prow[k], w_rff[k], part);
    #pragma unroll
    for (int off = 32; off > 0; off >>= 1) part += __shfl_down(part, off, 64);
    if ((tid & 63) == 0) wsum[tid >> 6] = part;
    __syncthreads();
    if (tid == 0) {
        const float tot = wsum[0] + wsum[1] + wsum[2] + wsum[3];
        out_r[r] = selu_f(tot + b_rff[0]);
    }
}

// Kernel D1: partial GEMV tiles for the product head. grid (NCG,NKG), block 256.
__global__ __launch_bounds__(256) void k_prod_partial(
        const float* __restrict__ p_batch,  // [64,532]
        const float* __restrict__ w_prod,   // [532,532]
        float* __restrict__ part)           // out [NKG][532]
{
    __shared__ float pbar[PCHUNK];
    __shared__ float red[2][PCHUNK];
    const int cg = blockIdx.x, kg = blockIdx.y;
    const int tid = threadIdx.x;
    const int cl = tid & (PCHUNK - 1);
    const int h  = tid >> 7;                 // 0 or 1
    const int k0 = kg * PCHUNK;
    const int klen = min(PCHUNK, D_ - k0);

    if (cl < klen) {
        float s = 0.f;
        #pragma unroll 8
        for (int r = h * 32; r < h * 32 + 32; ++r)
            s += p_batch[(size_t)r * D_ + k0 + cl];
        red[h][cl] = s;
    }
    __syncthreads();
    if (h == 0 && cl < klen) pbar[cl] = (red[0][cl] + red[1][cl]) * (1.0f / 64.0f);
    __syncthreads();

    const int c = cg * PCHUNK + cl;
    float acc = 0.f;
    if (c < D_) {
        const int jb = h * 64;
        const int je = min(jb + 64, klen);
        for (int j = jb; j < je; ++j)
            acc = fmaf(pbar[j], w_prod[(size_t)(k0 + j) * D_ + c], acc);
    }
    red[h][cl] = acc;
    __syncthreads();
    if (h == 0 && c < D_) part[kg * D_ + c] = red[0][cl] + red[1][cl];
}

// Kernel D2: reduce partials + bias + SELU -> hn; then p_stars = selu(hn @ w_pff + b_pff).
__global__ __launch_bounds__(256) void k_prod_final(
        const float* __restrict__ part,    // [NKG][532]
        const float* __restrict__ b_prod,  // [532]
        const float* __restrict__ w_pff,   // [532,9]
        const float* __restrict__ b_pff,   // [9]
        float* __restrict__ out_p)         // p_stars [9]
{
    __shared__ float hn[D_];
    const int tid = threadIdx.x;
    for (int c = tid; c < D_; c += 256) {
        float s = b_prod[c];
        #pragma unroll
        for (int kg = 0; kg < NKG; ++kg) s += part[kg * D_ + c];
        hn[c] = selu_f(s);
    }
    __syncthreads();
    if (tid < L_) {
        float a = 0.f;
        for (int k = 0; k < D_; ++k) a = fmaf(hn[k], w_pff[k * L_ + tid], a);
        out_p[tid] = selu_f(a + b_pff[tid]);
    }
}

extern "C" void kernel_launch(void* const* d_in, const int* in_sizes, int n_in,
                              void* d_out, int out_size, void* d_ws, size_t ws_size,
                              hipStream_t stream) {
    const int*   inputs     = (const int*)  d_in[0];
    const float* user_feats = (const float*)d_in[1];
    const float* emb        = (const float*)d_in[2];
    const float* w_sent     = (const float*)d_in[3];
    const float* b_sent     = (const float*)d_in[4];
    const float* w_rev      = (const float*)d_in[5];
    const float* b_rev      = (const float*)d_in[6];
    const float* w_prod     = (const float*)d_in[7];
    const float* b_prod     = (const float*)d_in[8];
    const float* w_rff      = (const float*)d_in[9];
    const float* b_rff      = (const float*)d_in[10];
    const float* w_pff      = (const float*)d_in[11];
    const float* b_pff      = (const float*)d_in[12];
    const float* user_w     = (const float*)d_in[13];
    float* out = (float*)d_out;   // [0..8] p_stars, [9..72] r_stars

    // workspace layout (float units, all 16B-aligned)
    float* ws = (float*)d_ws;
    __hip_bfloat16* sent_bf  = (__hip_bfloat16*)(ws);            // 2048*512 bf16 = 524288 f
    __hip_bfloat16* sent_hbf = (__hip_bfloat16*)(ws + 524288);   // 2048*512 bf16
    __hip_bfloat16* wT       = (__hip_bfloat16*)(ws + 1048576);  // 512*512 bf16 = 131072 f
    float* smask   = ws + 1179648;   // 2048
    float* p_batch = ws + 1181696;   // 64*532
    float* part    = ws + 1215744;   // NKG*532

    k_fused_A<<<NSENT + 256, 256, 0, stream>>>(inputs, emb, w_sent, sent_bf, wT, smask);
    k_gemm_selu<<<dim3(E_ / 64, NSENT / 64), 256, 0, stream>>>(
        sent_bf, wT, b_sent, sent_hbf, E_);
    k_rev_fused<<<R_, 256, 0, stream>>>(sent_hbf, smask, w_rev, b_rev, user_feats, user_w,
                                        w_rff, b_rff, p_batch, out + L_);
    k_prod_partial<<<dim3(NCG, NKG), 256, 0, stream>>>(p_batch, w_prod, part);
    k_prod_final<<<1, 256, 0, stream>>>(part, b_prod, w_pff, b_pff, out);
}

// Round 5
// 80.036 us; speedup vs baseline: 1.1849x; 1.1849x over previous
//
#include <hip/hip_runtime.h>
#include <hip/hip_bf16.h>

// Model dims (fixed by the reference)
#define R_ 64
#define S_ 32
#define T_ 50
#define E_ 512
#define U_ 20
#define D_ 532   // E + U
#define L_ 9
#define NSENT (R_ * S_)   // 2048

#define PCHUNK 128
#define NCG 5   // ceil(532/128) column groups
#define NKG 5   // ceil(532/128) k groups

typedef __attribute__((ext_vector_type(8))) short bf16x8;
typedef __attribute__((ext_vector_type(4))) float f32x4;

__device__ __forceinline__ float selu_f(float x) {
    const float scale = 1.0507009873554805f;
    const float alpha = 1.6732632423543772f;
    return x > 0.0f ? scale * x : scale * alpha * expm1f(x);
}

__device__ __forceinline__ void store_out(float* p, float v) { *p = v; }
__device__ __forceinline__ void store_out(__hip_bfloat16* p, float v) { *p = __float2bfloat16(v); }

// Kernel A (fused): blocks [0,2048) = per-sentence masked token-mean -> bf16.
// blocks [2048,2560) = transpose-convert {w_sent, w_rev} fp32 [k][n] -> bf16 wT[z][n][k].
__global__ __launch_bounds__(256) void k_fused_A(
        const int* __restrict__ inputs,       // [R,S,T]
        const float* __restrict__ emb,        // [V,E]
        const float* __restrict__ w_sent,     // [512,512]
        const float* __restrict__ w_rev,      // [512,512]
        __hip_bfloat16* __restrict__ sent_bf, // out [2048,512] bf16
        __hip_bfloat16* __restrict__ wT,      // out [2][512][512] bf16 (transposed)
        float* __restrict__ smask)            // out [2048]
{
    const int tid = threadIdx.x;

    if (blockIdx.x >= NSENT) {
        // ---- weight transpose-convert: 512 blocks of 32x32 tiles ----
        __shared__ float tile[32][33];
        const int b = blockIdx.x - NSENT;                 // 0..511
        const int z = b >> 8;                             // 0: w_sent, 1: w_rev
        const float* w = z ? w_rev : w_sent;
        __hip_bfloat16* o = wT + (size_t)z * E_ * E_;
        const int bb = b & 255;
        const int tx = tid & 31, ty = tid >> 5;           // ty 0..7
        const int k0 = (bb >> 4) * 32, n0 = (bb & 15) * 32;
        #pragma unroll
        for (int i = 0; i < 4; ++i)
            tile[ty + 8 * i][tx] = w[(size_t)(k0 + ty + 8 * i) * E_ + n0 + tx];
        __syncthreads();
        #pragma unroll
        for (int i = 0; i < 4; ++i)
            o[(size_t)(n0 + ty + 8 * i) * E_ + k0 + tx] = __float2bfloat16(tile[tx][ty + 8 * i]);
        return;
    }

    // ---- sentence masked mean (256 threads x float2; unconditional gather) ----
    const int sid = blockIdx.x;
    const int base = sid * T_;
    float2 acc = {0.f, 0.f};
    int cnt = 0;
    for (int t = 0; t < T_; ++t) {
        const int tok = inputs[base + t];     // wave-uniform -> scalar broadcast
        const float m = (tok != 0) ? 1.0f : 0.0f;
        cnt += (tok != 0);
        // unconditional load (tok==0 reads row 0, nullified by m) -> pipelinable
        const float2 v = ((const float2*)(emb + (size_t)tok * E_))[tid];
        acc.x = fmaf(v.x, m, acc.x);
        acc.y = fmaf(v.y, m, acc.y);
    }
    const float inv = 1.0f / fmaxf((float)cnt, 1.0f);
    __hip_bfloat162 h2;
    h2.x = __float2bfloat16(acc.x * inv);
    h2.y = __float2bfloat16(acc.y * inv);
    ((__hip_bfloat162*)(sent_bf + (size_t)sid * E_))[tid] = h2;
    if (tid == 0) smask[sid] = (cnt > 0) ? 1.0f : 0.0f;   // tokens >= 0, so sum!=0 <=> any!=0
}

// Kernel G: C[M,512] = selu(A_bf16[M,512] @ W + bias), W given transposed bf16 (Bt[n][k]).
// 64x64 tile per block, 4 waves in 2x2, each wave 32x32 via 2x2 mfma_f32_16x16x32_bf16.
// grid = (N/64, M/64), block 256.
template <typename OutT>
__global__ __launch_bounds__(256) void k_gemm_selu(
        const __hip_bfloat16* __restrict__ A,   // [M,512]
        const __hip_bfloat16* __restrict__ Bt,  // [512,512]  Bt[n][k]
        const float* __restrict__ bias,         // [512]
        OutT* __restrict__ C, int ldc)
{
    __shared__ short As[64][40];   // 64 rows x (32 k + 8 pad) bf16
    __shared__ short Bs[64][40];
    const int tid  = threadIdx.x;
    const int wid  = tid >> 6;
    const int lane = tid & 63;
    const int wm = wid >> 1, wn = wid & 1;
    const int bm = blockIdx.y * 64, bn = blockIdx.x * 64;

    const int srow = tid >> 2;         // 0..63
    const int soff = (tid & 3) * 8;    // 0,8,16,24

    const short* Ag  = (const short*)A;
    const short* Btg = (const short*)Bt;

    f32x4 acc[2][2];
    #pragma unroll
    for (int i = 0; i < 2; ++i)
        #pragma unroll
        for (int j = 0; j < 2; ++j) acc[i][j] = (f32x4){0.f, 0.f, 0.f, 0.f};

    const int fr = lane & 15;
    const int kg = (lane >> 4) * 8;

    for (int k0 = 0; k0 < E_; k0 += 32) {
        __syncthreads();
        *(bf16x8*)&As[srow][soff] = *(const bf16x8*)&Ag[(size_t)(bm + srow) * E_ + k0 + soff];
        *(bf16x8*)&Bs[srow][soff] = *(const bf16x8*)&Btg[(size_t)(bn + srow) * E_ + k0 + soff];
        __syncthreads();
        bf16x8 af0 = *(const bf16x8*)&As[wm * 32 + fr][kg];
        bf16x8 af1 = *(const bf16x8*)&As[wm * 32 + 16 + fr][kg];
        bf16x8 bf0 = *(const bf16x8*)&Bs[wn * 32 + fr][kg];
        bf16x8 bf1 = *(const bf16x8*)&Bs[wn * 32 + 16 + fr][kg];
        acc[0][0] = __builtin_amdgcn_mfma_f32_16x16x32_bf16(af0, bf0, acc[0][0], 0, 0, 0);
        acc[0][1] = __builtin_amdgcn_mfma_f32_16x16x32_bf16(af0, bf1, acc[0][1], 0, 0, 0);
        acc[1][0] = __builtin_amdgcn_mfma_f32_16x16x32_bf16(af1, bf0, acc[1][0], 0, 0, 0);
        acc[1][1] = __builtin_amdgcn_mfma_f32_16x16x32_bf16(af1, bf1, acc[1][1], 0, 0, 0);
    }

    // epilogue: C/D mapping col = lane&15, row = (lane>>4)*4 + reg   [m89]
    const int rq = (lane >> 4) * 4;
    #pragma unroll
    for (int fm = 0; fm < 2; ++fm) {
        #pragma unroll
        for (int fn = 0; fn < 2; ++fn) {
            const int col = bn + wn * 32 + fn * 16 + fr;
            const float bv = bias[col];
            #pragma unroll
            for (int j = 0; j < 4; ++j) {
                const int row = bm + wm * 32 + fm * 16 + rq + j;
                store_out(&C[(size_t)row * ldc + col], selu_f(acc[fm][fn][j] + bv));
            }
        }
    }
}

// Kernel RM: per-review masked mean over sentences (bf16 in, bf16 out).
// grid = 64, block 256 (each thread 2 cols).
__global__ __launch_bounds__(256) void k_rev_mean(
        const __hip_bfloat16* __restrict__ sent_h,  // [2048,512] bf16
        const float* __restrict__ smask,            // [2048]
        __hip_bfloat16* __restrict__ mrev)          // out [64,512] bf16
{
    const int r = blockIdx.x;
    const int tid = threadIdx.x;
    float2 acc = {0.f, 0.f};
    float msum = 0.f;
    for (int s = 0; s < S_; ++s) {
        const float m = smask[r * S_ + s];
        const __hip_bfloat162 v = ((const __hip_bfloat162*)(sent_h + (size_t)(r * S_ + s) * E_))[tid];
        acc.x = fmaf(__bfloat162float(v.x), m, acc.x);
        acc.y = fmaf(__bfloat162float(v.y), m, acc.y);
        msum += m;
    }
    const float inv = 1.0f / fmaxf(msum, 1.0f);
    __hip_bfloat162 h2;
    h2.x = __float2bfloat16(acc.x * inv);
    h2.y = __float2bfloat16(acc.y * inv);
    ((__hip_bfloat162*)(mrev + (size_t)r * E_))[tid] = h2;
}

// Kernel PB: fill p_batch user-feat columns + compute r_stars.
// grid = 64 (one review), block 64 (one wave).
__global__ __launch_bounds__(64) void k_pbatch(
        const float* __restrict__ user_feats, // [64,20]
        const float* __restrict__ user_w,     // [20]
        const float* __restrict__ w_rff,      // [532]
        const float* __restrict__ b_rff,      // [1]
        float* __restrict__ p_batch,          // [64,532]; cols 0..511 pre-filled by rev GEMM
        float* __restrict__ out_r)            // r_stars [64]
{
    __shared__ float uf[U_];
    const int r = blockIdx.x;
    const int tid = threadIdx.x;
    if (tid < U_) {
        float ss = 0.f;
        #pragma unroll
        for (int j = 0; j < U_; ++j) {
            const float u = user_feats[r * U_ + j];
            ss = fmaf(u, u, ss);
        }
        const float nrm = fmaxf(sqrtf(ss), 1e-12f);
        const float v = user_feats[r * U_ + tid] / nrm * user_w[tid];
        uf[tid] = v;
        p_batch[(size_t)r * D_ + E_ + tid] = v;
    }
    __syncthreads();
    float part = 0.f;
    #pragma unroll
    for (int i = 0; i < 8; ++i)
        part = fmaf(p_batch[(size_t)r * D_ + tid + 64 * i], w_rff[tid + 64 * i], part);
    if (tid < U_) part = fmaf(uf[tid], w_rff[E_ + tid], part);
    #pragma unroll
    for (int off = 32; off > 0; off >>= 1) part += __shfl_down(part, off, 64);
    if (tid == 0) out_r[r] = selu_f(part + b_rff[0]);
}

// Kernel D1: partial GEMV tiles for the product head. grid (NCG,NKG), block 256.
__global__ __launch_bounds__(256) void k_prod_partial(
        const float* __restrict__ p_batch,  // [64,532]
        const float* __restrict__ w_prod,   // [532,532]
        float* __restrict__ part)           // out [NKG][532]
{
    __shared__ float pbar[PCHUNK];
    __shared__ float red[2][PCHUNK];
    const int cg = blockIdx.x, kg = blockIdx.y;
    const int tid = threadIdx.x;
    const int cl = tid & (PCHUNK - 1);
    const int h  = tid >> 7;                 // 0 or 1
    const int k0 = kg * PCHUNK;
    const int klen = min(PCHUNK, D_ - k0);

    if (cl < klen) {
        float s = 0.f;
        #pragma unroll 8
        for (int r = h * 32; r < h * 32 + 32; ++r)
            s += p_batch[(size_t)r * D_ + k0 + cl];
        red[h][cl] = s;
    }
    __syncthreads();
    if (h == 0 && cl < klen) pbar[cl] = (red[0][cl] + red[1][cl]) * (1.0f / 64.0f);
    __syncthreads();

    const int c = cg * PCHUNK + cl;
    float acc = 0.f;
    if (c < D_) {
        const int jb = h * 64;
        const int je = min(jb + 64, klen);
        for (int j = jb; j < je; ++j)
            acc = fmaf(pbar[j], w_prod[(size_t)(k0 + j) * D_ + c], acc);
    }
    red[h][cl] = acc;
    __syncthreads();
    if (h == 0 && c < D_) part[kg * D_ + c] = red[0][cl] + red[1][cl];
}

// Kernel D2: reduce partials + bias + SELU -> hn; then p_stars = selu(hn @ w_pff + b_pff).
__global__ __launch_bounds__(256) void k_prod_final(
        const float* __restrict__ part,    // [NKG][532]
        const float* __restrict__ b_prod,  // [532]
        const float* __restrict__ w_pff,   // [532,9]
        const float* __restrict__ b_pff,   // [9]
        float* __restrict__ out_p)         // p_stars [9]
{
    __shared__ float hn[D_];
    const int tid = threadIdx.x;
    for (int c = tid; c < D_; c += 256) {
        float s = b_prod[c];
        #pragma unroll
        for (int kg = 0; kg < NKG; ++kg) s += part[kg * D_ + c];
        hn[c] = selu_f(s);
    }
    __syncthreads();
    if (tid < L_) {
        float a = 0.f;
        for (int k = 0; k < D_; ++k) a = fmaf(hn[k], w_pff[k * L_ + tid], a);
        out_p[tid] = selu_f(a + b_pff[tid]);
    }
}

extern "C" void kernel_launch(void* const* d_in, const int* in_sizes, int n_in,
                              void* d_out, int out_size, void* d_ws, size_t ws_size,
                              hipStream_t stream) {
    const int*   inputs     = (const int*)  d_in[0];
    const float* user_feats = (const float*)d_in[1];
    const float* emb        = (const float*)d_in[2];
    const float* w_sent     = (const float*)d_in[3];
    const float* b_sent     = (const float*)d_in[4];
    const float* w_rev      = (const float*)d_in[5];
    const float* b_rev      = (const float*)d_in[6];
    const float* w_prod     = (const float*)d_in[7];
    const float* b_prod     = (const float*)d_in[8];
    const float* w_rff      = (const float*)d_in[9];
    const float* b_rff      = (const float*)d_in[10];
    const float* w_pff      = (const float*)d_in[11];
    const float* b_pff      = (const float*)d_in[12];
    const float* user_w     = (const float*)d_in[13];
    float* out = (float*)d_out;   // [0..8] p_stars, [9..72] r_stars

    // workspace layout (float units, all 16B-aligned) — same as R3 (82 us baseline)
    float* ws = (float*)d_ws;
    __hip_bfloat16* sent_bf  = (__hip_bfloat16*)(ws);            // 2048*512 bf16 = 524288 f
    __hip_bfloat16* sent_hbf = (__hip_bfloat16*)(ws + 524288);   // 2048*512 bf16
    __hip_bfloat16* wT       = (__hip_bfloat16*)(ws + 1048576);  // 2*512*512 bf16 = 262144 f
    __hip_bfloat16* mrev     = (__hip_bfloat16*)(ws + 1310720);  // 64*512 bf16 = 16384 f
    float* smask   = ws + 1327104;   // 2048
    float* p_batch = ws + 1329152;   // 64*532
    float* part    = ws + 1363200;   // NKG*532

    k_fused_A<<<NSENT + 512, 256, 0, stream>>>(inputs, emb, w_sent, w_rev,
                                               sent_bf, wT, smask);
    k_gemm_selu<__hip_bfloat16><<<dim3(E_ / 64, NSENT / 64), 256, 0, stream>>>(
        sent_bf, wT, b_sent, sent_hbf, E_);
    k_rev_mean<<<R_, 256, 0, stream>>>(sent_hbf, smask, mrev);
    k_gemm_selu<float><<<dim3(E_ / 64, R_ / 64), 256, 0, stream>>>(
        mrev, wT + (size_t)E_ * E_, b_rev, p_batch, D_);
    k_pbatch<<<R_, 64, 0, stream>>>(user_feats, user_w, w_rff, b_rff, p_batch, out + L_);
    k_prod_partial<<<dim3(NCG, NKG), 256, 0, stream>>>(p_batch, w_prod, part);
    k_prod_final<<<1, 256, 0, stream>>>(part, b_prod, w_pff, b_pff, out);
}